// Round 15
// baseline (222.714 us; speedup 1.0000x reference)
//
#include <hip/hip_runtime.h>

typedef __attribute__((ext_vector_type(8))) _Float16 f16x8;
typedef __attribute__((ext_vector_type(4))) _Float16 f16x4;
typedef __attribute__((ext_vector_type(4))) float    f32x4;

constexpr int Bsz = 32768;
constexpr int Hn  = 256;
constexpr int In  = 128;
constexpr long long BH = (long long)Bsz * Hn;

// ---------------------------------------------------------------------------
// prep: weights -> fp16, PRE-SWIZZLED into MFMA-fragment-linear order.
// Tile (cg, t): lane l holds W[cg*16 + (l&15)][t*32 + (l>>4)*8 ..+8],
// stored at ((cg*NT + t)*64 + l)*8 halves.
// ws half-layout: Gh [0,64K) | Gm [64K,128K) | Wr [128K,192K) | Wi [192K,224K)
// ---------------------------------------------------------------------------
__global__ __launch_bounds__(256) void k_prep(
    const float* __restrict__ Wi, const float* __restrict__ Wr,
    const float* __restrict__ Gc, _Float16* __restrict__ ws)
{
    const int idx = blockIdx.x * 256 + threadIdx.x;   // 0..65535
    {   // Gh/Gm/Wr: K=256, NT=8
        const int cg = idx >> 12, rem = idx & 4095;
        const int t = rem >> 9, l = (rem >> 3) & 63, j = idx & 7;
        const int col = cg * 16 + (l & 15);
        const int k   = t * 32 + (l >> 4) * 8 + j;
        float g = Gc[col * Hn + k];
        _Float16 gh = (_Float16)g;
        ws[idx]         = gh;
        ws[65536 + idx] = (_Float16)((g - (float)gh) * 4096.0f);
        ws[131072 + idx] = (_Float16)Wr[col * Hn + k];
    }
    if (idx < 32768) {  // Wi: K=128, NT=4
        const int cg = idx >> 11, rem = idx & 2047;
        const int t = rem >> 9, l = (rem >> 3) & 63, j = idx & 7;
        const int col = cg * 16 + (l & 15);
        const int k   = t * 32 + (l >> 4) * 8 + j;
        ws[196608 + idx] = (_Float16)Wi[col * In + k];
    }
}

// LDS swizzled byte offsets
__device__ __forceinline__ int swzH(int row, int colh) {   // fp16 [32][256]
    return (row * 512 + colh * 2) ^ ((row & 7) << 4);
}
__device__ __forceinline__ int swzO(int row, int col4) {   // fp32 [32][256]
    return (row * 1024 + col4 * 4) ^ ((row & 7) << 4);
}

__device__ __forceinline__ f16x4 cvt4h(float4 a) {
    f16x4 r;
    r[0] = (_Float16)a.x; r[1] = (_Float16)a.y;
    r[2] = (_Float16)a.z; r[3] = (_Float16)a.w;
    return r;
}
__device__ __forceinline__ f16x4 cvt4m(float4 a) {
    float f[4] = {a.x, a.y, a.z, a.w};
    f16x4 r;
    #pragma unroll
    for (int k = 0; k < 4; ++k) {
        _Float16 h = (_Float16)f[k];
        r[k] = (_Float16)((f[k] - (float)h) * 4096.0f);
    }
    return r;
}
__device__ __forceinline__ f16x8 cvt_hi2(float4 a, float4 b) {
    float f[8] = {a.x, a.y, a.z, a.w, b.x, b.y, b.z, b.w};
    f16x8 r;
    #pragma unroll
    for (int k = 0; k < 8; ++k) r[k] = (_Float16)f[k];
    return r;
}

#define MFMA16(A, B, C) __builtin_amdgcn_mfma_f32_16x16x32_f16(A, B, C, 0, 0, 0)

// ---------------------------------------------------------------------------
// main: 1024 blocks x 512 thr (8 waves), BT=32. LDS 48 KB -> 3 blocks/CU:
//   k-loop: VH 16K | VM 16K | ZH 16K   (x-fragments direct from global, t<4)
//   epilogue: Oc fp32 32K (aliases VH+VM) | Oi fp16 16K (aliases ZH)
// 3 barriers; fragment values + MFMA order identical to R11 for z/v/rho
// (bit-identical); i_new picks up <=0.004 extra error from fp16 Oi staging.
// ---------------------------------------------------------------------------
__global__ __launch_bounds__(512, 6) void k_main(
    const float* __restrict__ x, const float* __restrict__ z,
    const float* __restrict__ v, const float* __restrict__ cur,
    const float* __restrict__ rho, const _Float16* __restrict__ ws,
    float* __restrict__ out)
{
    __shared__ char smem[49152];
    char* VH = smem;             // 16 KB fp16 [32][256]
    char* VM = smem + 16384;     // 16 KB
    char* ZH = smem + 32768;     // 16 KB
    char* Oc = smem;             // 32 KB fp32 (epilogue, aliases VH+VM)
    char* Oi = smem + 32768;     // 16 KB fp16 (epilogue, aliases ZH)

    const int tid  = threadIdx.x;         // 0..511
    const int lane = tid & 63;
    const int ln = lane & 15, lg = lane >> 4;
    const int w  = tid >> 6;              // wave 0..7
    const int rowBase = blockIdx.x * 32;

    // ---- stage V, Z: coalesced 1-KB wave reads; convert to fp16 once ----
    {
        const float4* vsrc = (const float4*)(v + (size_t)rowBase * Hn);
        const float4* zsrc = (const float4*)(z + (size_t)rowBase * Hn);
        #pragma unroll
        for (int k = 0; k < 4; ++k) {
            const int f = k * 512 + tid;          // float4 index, 0..2047
            const int row = f >> 6, c4 = (f & 63) * 4;
            float4 a = vsrc[f];
            *(f16x4*)(VH + swzH(row, c4)) = cvt4h(a);
            *(f16x4*)(VM + swzH(row, c4)) = cvt4m(a);
        }
        #pragma unroll
        for (int k = 0; k < 4; ++k) {
            const int f = k * 512 + tid;
            const int row = f >> 6, c4 = (f & 63) * 4;
            *(f16x4*)(ZH + swzH(row, c4)) = cvt4h(zsrc[f]);
        }
    }
    __syncthreads();                                   // barrier 1

    f32x4 acc_c[2][2], acc_cm[2][2], acc_i[2][2];
    #pragma unroll
    for (int m = 0; m < 2; ++m)
        #pragma unroll
        for (int c = 0; c < 2; ++c) {
            acc_c[m][c]  = (f32x4){0.f, 0.f, 0.f, 0.f};
            acc_cm[m][c] = (f32x4){0.f, 0.f, 0.f, 0.f};
            acc_i[m][c]  = (f32x4){0.f, 0.f, 0.f, 0.f};
        }

    const _Float16* Gh  = ws;
    const _Float16* Gm  = ws + 65536;
    const _Float16* Wr  = ws + 131072;
    const _Float16* Wi  = ws + 196608;

    // per-lane x row pointers (rows ln and ln+16; small, L1/L3-served)
    const float* xr0 = x + (size_t)(rowBase + ln) * In;
    const float* xr1 = xr0 + 16 * In;

    // ---- main loop: 8 k-steps of 32; no barriers ----
    #pragma unroll 2
    for (int t = 0; t < 8; ++t) {
        const int kf = t * 32 + lg * 8;
        f16x8 vh0 = *(const f16x8*)(VH + swzH(ln,      kf));
        f16x8 vh1 = *(const f16x8*)(VH + swzH(ln + 16, kf));
        f16x8 vm0 = *(const f16x8*)(VM + swzH(ln,      kf));
        f16x8 vm1 = *(const f16x8*)(VM + swzH(ln + 16, kf));
        f16x8 zh0 = *(const f16x8*)(ZH + swzH(ln,      kf));
        f16x8 zh1 = *(const f16x8*)(ZH + swzH(ln + 16, kf));
        f16x8 xh0, xh1;
        if (t < 4) {
            float4 xa00 = *(const float4*)(xr0 + kf);
            float4 xa01 = *(const float4*)(xr0 + kf + 4);
            float4 xa10 = *(const float4*)(xr1 + kf);
            float4 xa11 = *(const float4*)(xr1 + kf + 4);
            xh0 = cvt_hi2(xa00, xa01);
            xh1 = cvt_hi2(xa10, xa11);
        }
        #pragma unroll
        for (int c = 0; c < 2; ++c) {
            const int cg = w * 2 + c;
            f16x8 bgh = *(const f16x8*)(Gh + ((size_t)(cg * 8 + t) * 64 + lane) * 8);
            f16x8 bgm = *(const f16x8*)(Gm + ((size_t)(cg * 8 + t) * 64 + lane) * 8);
            f16x8 bwr = *(const f16x8*)(Wr + ((size_t)(cg * 8 + t) * 64 + lane) * 8);
            acc_c[0][c]  = MFMA16(vh0, bgh, acc_c[0][c]);
            acc_c[1][c]  = MFMA16(vh1, bgh, acc_c[1][c]);
            acc_cm[0][c] = MFMA16(vh0, bgm, acc_cm[0][c]);
            acc_cm[1][c] = MFMA16(vh1, bgm, acc_cm[1][c]);
            acc_cm[0][c] = MFMA16(vm0, bgh, acc_cm[0][c]);
            acc_cm[1][c] = MFMA16(vm1, bgh, acc_cm[1][c]);
            acc_i[0][c]  = MFMA16(zh0, bwr, acc_i[0][c]);
            acc_i[1][c]  = MFMA16(zh1, bwr, acc_i[1][c]);
            if (t < 4) {
                f16x8 bwi = *(const f16x8*)(Wi + ((size_t)(cg * 4 + t) * 64 + lane) * 8);
                acc_i[0][c] = MFMA16(xh0, bwi, acc_i[0][c]);
                acc_i[1][c] = MFMA16(xh1, bwi, acc_i[1][c]);
            }
        }
    }

    // fold split-fp16 correction: coupling = acc_c + acc_cm / 4096
    #pragma unroll
    for (int m = 0; m < 2; ++m)
        #pragma unroll
        for (int c = 0; c < 2; ++c)
            acc_c[m][c] = acc_c[m][c] + acc_cm[m][c] * 2.44140625e-4f;

    // ---- all LDS reads done; overwrite with transpose tiles ----
    __syncthreads();                                   // barrier 2
    #pragma unroll
    for (int m = 0; m < 2; ++m)
        #pragma unroll
        for (int c = 0; c < 2; ++c) {
            const int col = (w * 2 + c) * 16 + ln;
            #pragma unroll
            for (int r = 0; r < 4; ++r) {
                const int row = m * 16 + lg * 4 + r;
                *(float*)(Oc + swzO(row, col)) = acc_c[m][c][r];
                *(_Float16*)(Oi + swzH(row, col)) = (_Float16)acc_i[m][c][r];
            }
        }

    // ---- issue epilogue loads before barrier (hide under drain) ----
    float4 vv4[4], ii4[4], rh4[4];
    #pragma unroll
    for (int j = 0; j < 4; ++j) {
        const int f = j * 512 + tid;                   // 0..2047
        const int row = f >> 6, c4 = (f & 63) * 4;
        const size_t gidx = (size_t)(rowBase + row) * Hn + c4;
        vv4[j] = *(const float4*)(v + gidx);
        ii4[j] = *(const float4*)(cur + gidx);
        rh4[j] = *(const float4*)(rho + gidx);
    }
    __syncthreads();                                   // barrier 3

    float* out_z   = out;
    float* out_v   = out + BH;
    float* out_i   = out + 2 * BH;
    float* out_rho = out + 3 * BH;

    // ---- single epilogue pass: 1-KB contiguous wave IO, all 4 outputs ----
    #pragma unroll
    for (int j = 0; j < 4; ++j) {
        const int f = j * 512 + tid;
        const int row = f >> 6, c4 = (f & 63) * 4;
        const size_t gidx = (size_t)(rowBase + row) * Hn + c4;
        float4 coup = *(const float4*)(Oc + swzO(row, c4));
        f16x4 aih   = *(const f16x4*)(Oi + swzH(row, c4));
        float zn[4], vn[4], rn[4];
        float vvv[4] = {vv4[j].x, vv4[j].y, vv4[j].z, vv4[j].w};
        float iii[4] = {ii4[j].x, ii4[j].y, ii4[j].z, ii4[j].w};
        float rrr[4] = {rh4[j].x, rh4[j].y, rh4[j].z, rh4[j].w};
        float cpp[4] = {coup.x, coup.y, coup.z, coup.w};
        float aif[4] = {(float)aih[0], (float)aih[1], (float)aih[2], (float)aih[3]};
        #pragma unroll
        for (int q = 0; q < 4; ++q) {
            float dv   = 0.1f * ((0.0f - vvv[q]) + iii[q]) + cpp[q];
            float vdec = vvv[q] + dv;
            float zf   = (vdec - 1.0f) > 0.0f ? 1.0f : 0.0f;
            float vnew = (1.0f - zf) * vdec;              // V_RESET = 0
            float mask = rrr[q] > 0.0f ? 1.0f : 0.0f;
            vnew = (1.0f - mask) * vnew + mask * vvv[q];
            zf   = (1.0f - mask) * zf;
            float rhon = (1.0f - zf) * fmaxf(rrr[q] - mask, 0.0f) + zf * 5.0f;
            zn[q] = zf; vn[q] = vnew; rn[q] = rhon;
        }
        *(float4*)(out_z + gidx)   = make_float4(zn[0], zn[1], zn[2], zn[3]);
        *(float4*)(out_v + gidx)   = make_float4(vn[0], vn[1], vn[2], vn[3]);
        *(float4*)(out_rho + gidx) = make_float4(rn[0], rn[1], rn[2], rn[3]);
        *(float4*)(out_i + gidx)   = make_float4(
            0.8f * iii[0] + aif[0], 0.8f * iii[1] + aif[1],
            0.8f * iii[2] + aif[2], 0.8f * iii[3] + aif[3]);
    }
}

extern "C" void kernel_launch(void* const* d_in, const int* in_sizes, int n_in,
                              void* d_out, int out_size, void* d_ws, size_t ws_size,
                              hipStream_t stream) {
    const float* x   = (const float*)d_in[0];
    const float* z   = (const float*)d_in[1];
    const float* v   = (const float*)d_in[2];
    const float* cur = (const float*)d_in[3];
    const float* rho = (const float*)d_in[4];
    const float* Wi  = (const float*)d_in[5];
    const float* Wr  = (const float*)d_in[6];
    const float* Gc  = (const float*)d_in[7];
    float* out = (float*)d_out;
    _Float16* ws = (_Float16*)d_ws;   // needs 458752 B

    hipLaunchKernelGGL(k_prep, dim3(256), dim3(256), 0, stream, Wi, Wr, Gc, ws);
    hipLaunchKernelGGL(k_main, dim3(Bsz / 32), dim3(512), 0, stream,
                       x, z, v, cur, rho, ws, out);
}

// Round 16
// 91.632 us; speedup vs baseline: 2.4305x; 2.4305x over previous
//
#include <hip/hip_runtime.h>

typedef __attribute__((ext_vector_type(8))) _Float16 f16x8;
typedef __attribute__((ext_vector_type(4))) _Float16 f16x4;
typedef __attribute__((ext_vector_type(4))) float    f32x4;

constexpr int Bsz = 32768;
constexpr int Hn  = 256;
constexpr int In  = 128;
constexpr long long BH = (long long)Bsz * Hn;

// ---------------------------------------------------------------------------
// prep: weights -> fp16, PRE-SWIZZLED into MFMA-fragment-linear order.
// Tile (cg, t): lane l holds W[cg*16 + (l&15)][t*32 + (l>>4)*8 ..+8],
// stored at ((cg*NT + t)*64 + l)*8 halves.
// ws half-layout: Gh [0,64K) | Gm [64K,128K) | Wr [128K,192K) | Wi [192K,224K)
// ---------------------------------------------------------------------------
__global__ __launch_bounds__(256) void k_prep(
    const float* __restrict__ Wi, const float* __restrict__ Wr,
    const float* __restrict__ Gc, _Float16* __restrict__ ws)
{
    const int idx = blockIdx.x * 256 + threadIdx.x;   // 0..65535
    {   // Gh/Gm/Wr: K=256, NT=8
        const int cg = idx >> 12, rem = idx & 4095;
        const int t = rem >> 9, l = (rem >> 3) & 63, j = idx & 7;
        const int col = cg * 16 + (l & 15);
        const int k   = t * 32 + (l >> 4) * 8 + j;
        float g = Gc[col * Hn + k];
        _Float16 gh = (_Float16)g;
        ws[idx]         = gh;
        ws[65536 + idx] = (_Float16)((g - (float)gh) * 4096.0f);
        ws[131072 + idx] = (_Float16)Wr[col * Hn + k];
    }
    if (idx < 32768) {  // Wi: K=128, NT=4
        const int cg = idx >> 11, rem = idx & 2047;
        const int t = rem >> 9, l = (rem >> 3) & 63, j = idx & 7;
        const int col = cg * 16 + (l & 15);
        const int k   = t * 32 + (l >> 4) * 8 + j;
        ws[196608 + idx] = (_Float16)Wi[col * In + k];
    }
}

// LDS swizzled byte offsets
__device__ __forceinline__ int swzH(int row, int colh) {   // fp16 [32][256]
    return (row * 512 + colh * 2) ^ ((row & 7) << 4);
}
__device__ __forceinline__ int swzO(int row, int col4) {   // fp32 [32][256]
    return (row * 1024 + col4 * 4) ^ ((row & 7) << 4);
}

__device__ __forceinline__ f16x4 cvt4h(float4 a) {
    f16x4 r;
    r[0] = (_Float16)a.x; r[1] = (_Float16)a.y;
    r[2] = (_Float16)a.z; r[3] = (_Float16)a.w;
    return r;
}
__device__ __forceinline__ f16x4 cvt4m(float4 a) {
    float f[4] = {a.x, a.y, a.z, a.w};
    f16x4 r;
    #pragma unroll
    for (int k = 0; k < 4; ++k) {
        _Float16 h = (_Float16)f[k];
        r[k] = (_Float16)((f[k] - (float)h) * 4096.0f);
    }
    return r;
}
__device__ __forceinline__ f16x8 cvt_hi2(float4 a, float4 b) {
    float f[8] = {a.x, a.y, a.z, a.w, b.x, b.y, b.z, b.w};
    f16x8 r;
    #pragma unroll
    for (int k = 0; k < 8; ++k) r[k] = (_Float16)f[k];
    return r;
}

#define MFMA16(A, B, C) __builtin_amdgcn_mfma_f32_16x16x32_f16(A, B, C, 0, 0, 0)

// ---------------------------------------------------------------------------
// main: 1024 blocks x 512 thr (8 waves), BT=32. LDS 48 KB -> 3 blocks/CU:
//   k-loop: VH 16K | VM 16K | ZH 16K   (x-fragments direct from global, t<4)
//   epilogue: Oc fp32 32K (aliases VH+VM) | Oi fp16 16K (aliases ZH)
// __launch_bounds__(512, 4): the R11-proven register contract (VGPR cap 128,
// compiled to 64 spill-free); occupancy comes from the 48 KB LDS footprint.
// z/v/rho math bit-identical to R11; i_new +<=0.004 from fp16 Oi (R15-proven).
// ---------------------------------------------------------------------------
__global__ __launch_bounds__(512, 4) void k_main(
    const float* __restrict__ x, const float* __restrict__ z,
    const float* __restrict__ v, const float* __restrict__ cur,
    const float* __restrict__ rho, const _Float16* __restrict__ ws,
    float* __restrict__ out)
{
    __shared__ char smem[49152];
    char* VH = smem;             // 16 KB fp16 [32][256]
    char* VM = smem + 16384;     // 16 KB
    char* ZH = smem + 32768;     // 16 KB
    char* Oc = smem;             // 32 KB fp32 (epilogue, aliases VH+VM)
    char* Oi = smem + 32768;     // 16 KB fp16 (epilogue, aliases ZH)

    const int tid  = threadIdx.x;         // 0..511
    const int lane = tid & 63;
    const int ln = lane & 15, lg = lane >> 4;
    const int w  = tid >> 6;              // wave 0..7
    const int rowBase = blockIdx.x * 32;

    // ---- stage V, Z: coalesced 1-KB wave reads; convert to fp16 once ----
    {
        const float4* vsrc = (const float4*)(v + (size_t)rowBase * Hn);
        const float4* zsrc = (const float4*)(z + (size_t)rowBase * Hn);
        #pragma unroll
        for (int k = 0; k < 4; ++k) {
            const int f = k * 512 + tid;          // float4 index, 0..2047
            const int row = f >> 6, c4 = (f & 63) * 4;
            float4 a = vsrc[f];
            *(f16x4*)(VH + swzH(row, c4)) = cvt4h(a);
            *(f16x4*)(VM + swzH(row, c4)) = cvt4m(a);
        }
        #pragma unroll
        for (int k = 0; k < 4; ++k) {
            const int f = k * 512 + tid;
            const int row = f >> 6, c4 = (f & 63) * 4;
            *(f16x4*)(ZH + swzH(row, c4)) = cvt4h(zsrc[f]);
        }
    }
    __syncthreads();                                   // barrier 1

    f32x4 acc_c[2][2], acc_cm[2][2], acc_i[2][2];
    #pragma unroll
    for (int m = 0; m < 2; ++m)
        #pragma unroll
        for (int c = 0; c < 2; ++c) {
            acc_c[m][c]  = (f32x4){0.f, 0.f, 0.f, 0.f};
            acc_cm[m][c] = (f32x4){0.f, 0.f, 0.f, 0.f};
            acc_i[m][c]  = (f32x4){0.f, 0.f, 0.f, 0.f};
        }

    const _Float16* Gh  = ws;
    const _Float16* Gm  = ws + 65536;
    const _Float16* Wr  = ws + 131072;
    const _Float16* Wi  = ws + 196608;

    // per-lane x row pointers (rows ln and ln+16; small, L1/L3-served)
    const float* xr0 = x + (size_t)(rowBase + ln) * In;
    const float* xr1 = xr0 + 16 * In;

    // ---- main loop: 8 k-steps of 32; no barriers ----
    #pragma unroll 2
    for (int t = 0; t < 8; ++t) {
        const int kf = t * 32 + lg * 8;
        f16x8 vh0 = *(const f16x8*)(VH + swzH(ln,      kf));
        f16x8 vh1 = *(const f16x8*)(VH + swzH(ln + 16, kf));
        f16x8 vm0 = *(const f16x8*)(VM + swzH(ln,      kf));
        f16x8 vm1 = *(const f16x8*)(VM + swzH(ln + 16, kf));
        f16x8 zh0 = *(const f16x8*)(ZH + swzH(ln,      kf));
        f16x8 zh1 = *(const f16x8*)(ZH + swzH(ln + 16, kf));
        f16x8 xh0, xh1;
        if (t < 4) {
            float4 xa00 = *(const float4*)(xr0 + kf);
            float4 xa01 = *(const float4*)(xr0 + kf + 4);
            float4 xa10 = *(const float4*)(xr1 + kf);
            float4 xa11 = *(const float4*)(xr1 + kf + 4);
            xh0 = cvt_hi2(xa00, xa01);
            xh1 = cvt_hi2(xa10, xa11);
        }
        #pragma unroll
        for (int c = 0; c < 2; ++c) {
            const int cg = w * 2 + c;
            f16x8 bgh = *(const f16x8*)(Gh + ((size_t)(cg * 8 + t) * 64 + lane) * 8);
            f16x8 bgm = *(const f16x8*)(Gm + ((size_t)(cg * 8 + t) * 64 + lane) * 8);
            f16x8 bwr = *(const f16x8*)(Wr + ((size_t)(cg * 8 + t) * 64 + lane) * 8);
            acc_c[0][c]  = MFMA16(vh0, bgh, acc_c[0][c]);
            acc_c[1][c]  = MFMA16(vh1, bgh, acc_c[1][c]);
            acc_cm[0][c] = MFMA16(vh0, bgm, acc_cm[0][c]);
            acc_cm[1][c] = MFMA16(vh1, bgm, acc_cm[1][c]);
            acc_cm[0][c] = MFMA16(vm0, bgh, acc_cm[0][c]);
            acc_cm[1][c] = MFMA16(vm1, bgh, acc_cm[1][c]);
            acc_i[0][c]  = MFMA16(zh0, bwr, acc_i[0][c]);
            acc_i[1][c]  = MFMA16(zh1, bwr, acc_i[1][c]);
            if (t < 4) {
                f16x8 bwi = *(const f16x8*)(Wi + ((size_t)(cg * 4 + t) * 64 + lane) * 8);
                acc_i[0][c] = MFMA16(xh0, bwi, acc_i[0][c]);
                acc_i[1][c] = MFMA16(xh1, bwi, acc_i[1][c]);
            }
        }
    }

    // fold split-fp16 correction: coupling = acc_c + acc_cm / 4096
    #pragma unroll
    for (int m = 0; m < 2; ++m)
        #pragma unroll
        for (int c = 0; c < 2; ++c)
            acc_c[m][c] = acc_c[m][c] + acc_cm[m][c] * 2.44140625e-4f;

    // ---- all LDS reads done; overwrite with transpose tiles ----
    __syncthreads();                                   // barrier 2
    #pragma unroll
    for (int m = 0; m < 2; ++m)
        #pragma unroll
        for (int c = 0; c < 2; ++c) {
            const int col = (w * 2 + c) * 16 + ln;
            #pragma unroll
            for (int r = 0; r < 4; ++r) {
                const int row = m * 16 + lg * 4 + r;
                *(float*)(Oc + swzO(row, col)) = acc_c[m][c][r];
                *(_Float16*)(Oi + swzH(row, col)) = (_Float16)acc_i[m][c][r];
            }
        }

    // ---- issue epilogue loads before barrier (hide under drain) ----
    float4 vv4[4], ii4[4], rh4[4];
    #pragma unroll
    for (int j = 0; j < 4; ++j) {
        const int f = j * 512 + tid;                   // 0..2047
        const int row = f >> 6, c4 = (f & 63) * 4;
        const size_t gidx = (size_t)(rowBase + row) * Hn + c4;
        vv4[j] = *(const float4*)(v + gidx);
        ii4[j] = *(const float4*)(cur + gidx);
        rh4[j] = *(const float4*)(rho + gidx);
    }
    __syncthreads();                                   // barrier 3

    float* out_z   = out;
    float* out_v   = out + BH;
    float* out_i   = out + 2 * BH;
    float* out_rho = out + 3 * BH;

    // ---- single epilogue pass: 1-KB contiguous wave IO, all 4 outputs ----
    #pragma unroll
    for (int j = 0; j < 4; ++j) {
        const int f = j * 512 + tid;
        const int row = f >> 6, c4 = (f & 63) * 4;
        const size_t gidx = (size_t)(rowBase + row) * Hn + c4;
        float4 coup = *(const float4*)(Oc + swzO(row, c4));
        f16x4 aih   = *(const f16x4*)(Oi + swzH(row, c4));
        float zn[4], vn[4], rn[4];
        float vvv[4] = {vv4[j].x, vv4[j].y, vv4[j].z, vv4[j].w};
        float iii[4] = {ii4[j].x, ii4[j].y, ii4[j].z, ii4[j].w};
        float rrr[4] = {rh4[j].x, rh4[j].y, rh4[j].z, rh4[j].w};
        float cpp[4] = {coup.x, coup.y, coup.z, coup.w};
        float aif[4] = {(float)aih[0], (float)aih[1], (float)aih[2], (float)aih[3]};
        #pragma unroll
        for (int q = 0; q < 4; ++q) {
            float dv   = 0.1f * ((0.0f - vvv[q]) + iii[q]) + cpp[q];
            float vdec = vvv[q] + dv;
            float zf   = (vdec - 1.0f) > 0.0f ? 1.0f : 0.0f;
            float vnew = (1.0f - zf) * vdec;              // V_RESET = 0
            float mask = rrr[q] > 0.0f ? 1.0f : 0.0f;
            vnew = (1.0f - mask) * vnew + mask * vvv[q];
            zf   = (1.0f - mask) * zf;
            float rhon = (1.0f - zf) * fmaxf(rrr[q] - mask, 0.0f) + zf * 5.0f;
            zn[q] = zf; vn[q] = vnew; rn[q] = rhon;
        }
        *(float4*)(out_z + gidx)   = make_float4(zn[0], zn[1], zn[2], zn[3]);
        *(float4*)(out_v + gidx)   = make_float4(vn[0], vn[1], vn[2], vn[3]);
        *(float4*)(out_rho + gidx) = make_float4(rn[0], rn[1], rn[2], rn[3]);
        *(float4*)(out_i + gidx)   = make_float4(
            0.8f * iii[0] + aif[0], 0.8f * iii[1] + aif[1],
            0.8f * iii[2] + aif[2], 0.8f * iii[3] + aif[3]);
    }
}

extern "C" void kernel_launch(void* const* d_in, const int* in_sizes, int n_in,
                              void* d_out, int out_size, void* d_ws, size_t ws_size,
                              hipStream_t stream) {
    const float* x   = (const float*)d_in[0];
    const float* z   = (const float*)d_in[1];
    const float* v   = (const float*)d_in[2];
    const float* cur = (const float*)d_in[3];
    const float* rho = (const float*)d_in[4];
    const float* Wi  = (const float*)d_in[5];
    const float* Wr  = (const float*)d_in[6];
    const float* Gc  = (const float*)d_in[7];
    float* out = (float*)d_out;
    _Float16* ws = (_Float16*)d_ws;   // needs 458752 B

    hipLaunchKernelGGL(k_prep, dim3(256), dim3(256), 0, stream, Wi, Wr, Gc, ws);
    hipLaunchKernelGGL(k_main, dim3(Bsz / 32), dim3(512), 0, stream,
                       x, z, v, cur, rho, ws, out);
}

// Round 17
// 80.761 us; speedup vs baseline: 2.7577x; 1.1346x over previous
//
#include <hip/hip_runtime.h>

typedef __attribute__((ext_vector_type(8))) _Float16 f16x8;
typedef __attribute__((ext_vector_type(4))) _Float16 f16x4;
typedef __attribute__((ext_vector_type(4))) float    f32x4;

constexpr int Bsz = 32768;
constexpr int Hn  = 256;
constexpr int In  = 128;
constexpr long long BH = (long long)Bsz * Hn;

// ---------------------------------------------------------------------------
// prep: weights -> fp16, PRE-SWIZZLED into MFMA-fragment-linear order.
// Tile (cg, t): lane l holds W[cg*16 + (l&15)][t*32 + (l>>4)*8 ..+8],
// stored at ((cg*NT + t)*64 + l)*8 halves.
// ws half-layout: Gh [0,64K) | Gm [64K,128K) | Wr [128K,192K) | Wi [192K,224K)
// ---------------------------------------------------------------------------
__global__ __launch_bounds__(256) void k_prep(
    const float* __restrict__ Wi, const float* __restrict__ Wr,
    const float* __restrict__ Gc, _Float16* __restrict__ ws)
{
    const int idx = blockIdx.x * 256 + threadIdx.x;   // 0..65535
    {   // Gh/Gm/Wr: K=256, NT=8
        const int cg = idx >> 12, rem = idx & 4095;
        const int t = rem >> 9, l = (rem >> 3) & 63, j = idx & 7;
        const int col = cg * 16 + (l & 15);
        const int k   = t * 32 + (l >> 4) * 8 + j;
        float g = Gc[col * Hn + k];
        _Float16 gh = (_Float16)g;
        ws[idx]         = gh;
        ws[65536 + idx] = (_Float16)((g - (float)gh) * 4096.0f);
        ws[131072 + idx] = (_Float16)Wr[col * Hn + k];
    }
    if (idx < 32768) {  // Wi: K=128, NT=4
        const int cg = idx >> 11, rem = idx & 2047;
        const int t = rem >> 9, l = (rem >> 3) & 63, j = idx & 7;
        const int col = cg * 16 + (l & 15);
        const int k   = t * 32 + (l >> 4) * 8 + j;
        ws[196608 + idx] = (_Float16)Wi[col * In + k];
    }
}

// LDS swizzled byte offsets
__device__ __forceinline__ int swzH(int row, int colh) {   // fp16 [32][256]
    return (row * 512 + colh * 2) ^ ((row & 7) << 4);
}
__device__ __forceinline__ int swzX(int row, int colh) {   // fp16 [32][128]
    return (row * 256 + colh * 2) ^ ((row & 7) << 4);
}
__device__ __forceinline__ int swzO(int row, int col4) {   // fp32 [32][256]
    return (row * 1024 + col4 * 4) ^ ((row & 7) << 4);
}

__device__ __forceinline__ f16x4 cvt4h(float4 a) {
    f16x4 r;
    r[0] = (_Float16)a.x; r[1] = (_Float16)a.y;
    r[2] = (_Float16)a.z; r[3] = (_Float16)a.w;
    return r;
}
__device__ __forceinline__ f16x4 cvt4m(float4 a) {
    float f[4] = {a.x, a.y, a.z, a.w};
    f16x4 r;
    #pragma unroll
    for (int k = 0; k < 4; ++k) {
        _Float16 h = (_Float16)f[k];
        r[k] = (_Float16)((f[k] - (float)h) * 4096.0f);
    }
    return r;
}

#define MFMA16(A, B, C) __builtin_amdgcn_mfma_f32_16x16x32_f16(A, B, C, 0, 0, 0)

// ---------------------------------------------------------------------------
// main: 1024 blocks x 512 thr (8 waves), BT=32. LDS 56 KB (2 blocks/CU):
//   k-loop: VH 16K | VM 16K | ZH 16K | XH 8K  (all fp16, staged once)
//   epilogue: Oc fp32 32K (aliases VH+VM) | Oi fp16 16K (aliases ZH)
// Exact R11 structure (best measured: 80.8 us); single delta = fp16 Oi
// (verified harmless in R15/R16: absmax unchanged at 0.03125).
// z/v/rho math bit-identical to R8..R11.
// ---------------------------------------------------------------------------
__global__ __launch_bounds__(512, 4) void k_main(
    const float* __restrict__ x, const float* __restrict__ z,
    const float* __restrict__ v, const float* __restrict__ cur,
    const float* __restrict__ rho, const _Float16* __restrict__ ws,
    float* __restrict__ out)
{
    __shared__ char smem[57344];
    char* VH = smem;             // 16 KB fp16 [32][256]
    char* VM = smem + 16384;     // 16 KB
    char* ZH = smem + 32768;     // 16 KB
    char* XH = smem + 49152;     // 8 KB fp16 [32][128]
    char* Oc = smem;             // 32 KB fp32 (epilogue, aliases VH+VM)
    char* Oi = smem + 32768;     // 16 KB fp16 (epilogue, aliases ZH)

    const int tid  = threadIdx.x;         // 0..511
    const int lane = tid & 63;
    const int ln = lane & 15, lg = lane >> 4;
    const int w  = tid >> 6;              // wave 0..7
    const int rowBase = blockIdx.x * 32;

    // ---- stage: coalesced 1-KB wave reads; convert to fp16 once ----
    {
        const float4* vsrc = (const float4*)(v + (size_t)rowBase * Hn);
        const float4* zsrc = (const float4*)(z + (size_t)rowBase * Hn);
        const float4* xsrc = (const float4*)(x + (size_t)rowBase * In);
        #pragma unroll
        for (int k = 0; k < 4; ++k) {
            const int f = k * 512 + tid;          // float4 index, 0..2047
            const int row = f >> 6, c4 = (f & 63) * 4;
            float4 a = vsrc[f];
            *(f16x4*)(VH + swzH(row, c4)) = cvt4h(a);
            *(f16x4*)(VM + swzH(row, c4)) = cvt4m(a);
        }
        #pragma unroll
        for (int k = 0; k < 4; ++k) {
            const int f = k * 512 + tid;
            const int row = f >> 6, c4 = (f & 63) * 4;
            *(f16x4*)(ZH + swzH(row, c4)) = cvt4h(zsrc[f]);
        }
        #pragma unroll
        for (int k = 0; k < 2; ++k) {
            const int f = k * 512 + tid;          // 0..1023
            const int row = f >> 5, c4 = (f & 31) * 4;
            *(f16x4*)(XH + swzX(row, c4)) = cvt4h(xsrc[f]);
        }
    }
    __syncthreads();                                   // barrier 1

    f32x4 acc_c[2][2], acc_cm[2][2], acc_i[2][2];
    #pragma unroll
    for (int m = 0; m < 2; ++m)
        #pragma unroll
        for (int c = 0; c < 2; ++c) {
            acc_c[m][c]  = (f32x4){0.f, 0.f, 0.f, 0.f};
            acc_cm[m][c] = (f32x4){0.f, 0.f, 0.f, 0.f};
            acc_i[m][c]  = (f32x4){0.f, 0.f, 0.f, 0.f};
        }

    const _Float16* Gh  = ws;
    const _Float16* Gm  = ws + 65536;
    const _Float16* Wr  = ws + 131072;
    const _Float16* Wi  = ws + 196608;

    // ---- main loop: 8 k-steps of 32; no barriers ----
    #pragma unroll 2
    for (int t = 0; t < 8; ++t) {
        const int kf = t * 32 + lg * 8;
        f16x8 vh0 = *(const f16x8*)(VH + swzH(ln,      kf));
        f16x8 vh1 = *(const f16x8*)(VH + swzH(ln + 16, kf));
        f16x8 vm0 = *(const f16x8*)(VM + swzH(ln,      kf));
        f16x8 vm1 = *(const f16x8*)(VM + swzH(ln + 16, kf));
        f16x8 zh0 = *(const f16x8*)(ZH + swzH(ln,      kf));
        f16x8 zh1 = *(const f16x8*)(ZH + swzH(ln + 16, kf));
        f16x8 xh0, xh1;
        if (t < 4) {
            xh0 = *(const f16x8*)(XH + swzX(ln,      kf));
            xh1 = *(const f16x8*)(XH + swzX(ln + 16, kf));
        }
        #pragma unroll
        for (int c = 0; c < 2; ++c) {
            const int cg = w * 2 + c;
            f16x8 bgh = *(const f16x8*)(Gh + ((size_t)(cg * 8 + t) * 64 + lane) * 8);
            f16x8 bgm = *(const f16x8*)(Gm + ((size_t)(cg * 8 + t) * 64 + lane) * 8);
            f16x8 bwr = *(const f16x8*)(Wr + ((size_t)(cg * 8 + t) * 64 + lane) * 8);
            acc_c[0][c]  = MFMA16(vh0, bgh, acc_c[0][c]);
            acc_c[1][c]  = MFMA16(vh1, bgh, acc_c[1][c]);
            acc_cm[0][c] = MFMA16(vh0, bgm, acc_cm[0][c]);
            acc_cm[1][c] = MFMA16(vh1, bgm, acc_cm[1][c]);
            acc_cm[0][c] = MFMA16(vm0, bgh, acc_cm[0][c]);
            acc_cm[1][c] = MFMA16(vm1, bgh, acc_cm[1][c]);
            acc_i[0][c]  = MFMA16(zh0, bwr, acc_i[0][c]);
            acc_i[1][c]  = MFMA16(zh1, bwr, acc_i[1][c]);
            if (t < 4) {
                f16x8 bwi = *(const f16x8*)(Wi + ((size_t)(cg * 4 + t) * 64 + lane) * 8);
                acc_i[0][c] = MFMA16(xh0, bwi, acc_i[0][c]);
                acc_i[1][c] = MFMA16(xh1, bwi, acc_i[1][c]);
            }
        }
    }

    // fold split-fp16 correction: coupling = acc_c + acc_cm / 4096
    #pragma unroll
    for (int m = 0; m < 2; ++m)
        #pragma unroll
        for (int c = 0; c < 2; ++c)
            acc_c[m][c] = acc_c[m][c] + acc_cm[m][c] * 2.44140625e-4f;

    // ---- all LDS reads done; overwrite with transpose tiles ----
    __syncthreads();                                   // barrier 2
    #pragma unroll
    for (int m = 0; m < 2; ++m)
        #pragma unroll
        for (int c = 0; c < 2; ++c) {
            const int col = (w * 2 + c) * 16 + ln;
            #pragma unroll
            for (int r = 0; r < 4; ++r) {
                const int row = m * 16 + lg * 4 + r;
                *(float*)(Oc + swzO(row, col)) = acc_c[m][c][r];
                *(_Float16*)(Oi + swzH(row, col)) = (_Float16)acc_i[m][c][r];
            }
        }

    // ---- issue epilogue loads before barrier (hide under drain) ----
    float4 vv4[4], ii4[4], rh4[4];
    #pragma unroll
    for (int j = 0; j < 4; ++j) {
        const int f = j * 512 + tid;                   // 0..2047
        const int row = f >> 6, c4 = (f & 63) * 4;
        const size_t gidx = (size_t)(rowBase + row) * Hn + c4;
        vv4[j] = *(const float4*)(v + gidx);
        ii4[j] = *(const float4*)(cur + gidx);
        rh4[j] = *(const float4*)(rho + gidx);
    }
    __syncthreads();                                   // barrier 3

    float* out_z   = out;
    float* out_v   = out + BH;
    float* out_i   = out + 2 * BH;
    float* out_rho = out + 3 * BH;

    // ---- single epilogue pass: 1-KB contiguous wave IO, all 4 outputs ----
    #pragma unroll
    for (int j = 0; j < 4; ++j) {
        const int f = j * 512 + tid;
        const int row = f >> 6, c4 = (f & 63) * 4;
        const size_t gidx = (size_t)(rowBase + row) * Hn + c4;
        float4 coup = *(const float4*)(Oc + swzO(row, c4));
        f16x4 aih   = *(const f16x4*)(Oi + swzH(row, c4));
        float zn[4], vn[4], rn[4];
        float vvv[4] = {vv4[j].x, vv4[j].y, vv4[j].z, vv4[j].w};
        float iii[4] = {ii4[j].x, ii4[j].y, ii4[j].z, ii4[j].w};
        float rrr[4] = {rh4[j].x, rh4[j].y, rh4[j].z, rh4[j].w};
        float cpp[4] = {coup.x, coup.y, coup.z, coup.w};
        float aif[4] = {(float)aih[0], (float)aih[1], (float)aih[2], (float)aih[3]};
        #pragma unroll
        for (int q = 0; q < 4; ++q) {
            float dv   = 0.1f * ((0.0f - vvv[q]) + iii[q]) + cpp[q];
            float vdec = vvv[q] + dv;
            float zf   = (vdec - 1.0f) > 0.0f ? 1.0f : 0.0f;
            float vnew = (1.0f - zf) * vdec;              // V_RESET = 0
            float mask = rrr[q] > 0.0f ? 1.0f : 0.0f;
            vnew = (1.0f - mask) * vnew + mask * vvv[q];
            zf   = (1.0f - mask) * zf;
            float rhon = (1.0f - zf) * fmaxf(rrr[q] - mask, 0.0f) + zf * 5.0f;
            zn[q] = zf; vn[q] = vnew; rn[q] = rhon;
        }
        *(float4*)(out_z + gidx)   = make_float4(zn[0], zn[1], zn[2], zn[3]);
        *(float4*)(out_v + gidx)   = make_float4(vn[0], vn[1], vn[2], vn[3]);
        *(float4*)(out_rho + gidx) = make_float4(rn[0], rn[1], rn[2], rn[3]);
        *(float4*)(out_i + gidx)   = make_float4(
            0.8f * iii[0] + aif[0], 0.8f * iii[1] + aif[1],
            0.8f * iii[2] + aif[2], 0.8f * iii[3] + aif[3]);
    }
}

extern "C" void kernel_launch(void* const* d_in, const int* in_sizes, int n_in,
                              void* d_out, int out_size, void* d_ws, size_t ws_size,
                              hipStream_t stream) {
    const float* x   = (const float*)d_in[0];
    const float* z   = (const float*)d_in[1];
    const float* v   = (const float*)d_in[2];
    const float* cur = (const float*)d_in[3];
    const float* rho = (const float*)d_in[4];
    const float* Wi  = (const float*)d_in[5];
    const float* Wr  = (const float*)d_in[6];
    const float* Gc  = (const float*)d_in[7];
    float* out = (float*)d_out;
    _Float16* ws = (_Float16*)d_ws;   // needs 458752 B

    hipLaunchKernelGGL(k_prep, dim3(256), dim3(256), 0, stream, Wi, Wr, Gc, ws);
    hipLaunchKernelGGL(k_main, dim3(Bsz / 32), dim3(512), 0, stream,
                       x, z, v, cur, rho, ws, out);
}